// Round 4
// baseline (157.099 us; speedup 1.0000x reference)
//
#include <hip/hip_runtime.h>
#include <math.h>

#define NB 16384
typedef _Float16 h4 __attribute__((ext_vector_type(4)));

__device__ __forceinline__ float fast_sig(float v) { return __builtin_amdgcn_rcpf(1.0f + __expf(-v)); }
__device__ __forceinline__ float fast_tanh(float v) { return 1.0f - 2.0f * __builtin_amdgcn_rcpf(1.0f + __expf(2.0f * v)); }
#define WBAR() __builtin_amdgcn_wave_barrier()
#define LD4(p) (*(const float4*)(p))

// per-wave activation state: es (phase1) unions with {V, x} (decode). 1088 B.
struct __align__(16) WU { union { float es[240]; struct { float V[128]; float x[144]; } d; }; };

__global__ __launch_bounds__(256, 4) void decoder_kernel(
    const float* __restrict__ y,      // [B,13,4]
    const float* __restrict__ enc,    // [48,B,60]
    const float* __restrict__ hidden, // [B,30]
    const float* __restrict__ Wv, const float* __restrict__ bv,
    const float* __restrict__ Wg, const float* __restrict__ bg,
    const float* __restrict__ Wf1, const float* __restrict__ bf1,
    const float* __restrict__ Wf2, const float* __restrict__ bf2,
    const float* __restrict__ Wf3, const float* __restrict__ bf3,
    const float* __restrict__ Wih, const float* __restrict__ bih,
    const float* __restrict__ Whh, const float* __restrict__ bhh,
    float* __restrict__ out)          // [12,B]
{
    // All weights in f16 (activations & accumulation fp32 via v_fma_mix).
    // k-quads packed as half4 so one ds_read_b64 delivers 4 weights.
    __shared__ h4 s_W4h[68 * 30];   // [k][j]->(i,f,g,o); k 0..35 x-part (34,35 zero), 36..67 h-part (66,67 zero)
    __shared__ h4 s_Wgh[16 * 30];   // [kc][j] quads; kc 0..7 h-part, 8..15 V-part (pads zero)
    __shared__ h4 s_Wf1h[8 * 30];   // [kc][j]; covers k 0..31 (30 = se col, 31 zero)
    __shared__ h4 s_Wf2h[8 * 15];   // [kc][j2]; k 30,31 zero
    __shared__ h4 s_WvTh[15 * 30];  // [ec][j] quads of Wv^T
    __shared__ float4 s_b4[30];     // b_ih + b_hh per gate (fp32)
    __shared__ float s_bg[30], s_bf1[30], s_bf2[15], s_Wf3[15], s_bf3v;
    __shared__ float s_h[4][2][128]; // per-wave h double buffer: [wid][buf][4 rows x 32]
    __shared__ WU s_wu[4];

    const int t = threadIdx.x;
    const int lane = t & 63, wid = t >> 6;
    const int j = lane & 31, rg = lane >> 5;
    const int ra = rg * 2, rb = ra + 1;         // lane's two wave-local rows
    const int b0 = blockIdx.x * 16;
    const int bwg = b0 + wid * 4;               // wave's first global row
    WU& W = s_wu[wid];

    // ---------- phase 1a: enc mean over L=48 (coalesced float4) ----------
    float ax = 0, ay = 0, az = 0, aw = 0;
    int p1row = 0, p1c4 = 0;
    if (t < 240) {
        p1row = t / 15; p1c4 = t - p1row * 15;
        const float4* e4 = (const float4*)enc;
        const size_t base = (size_t)(b0 + p1row) * 15 + p1c4;
        #pragma unroll 4
        for (int l = 0; l < 48; ++l) {
            float4 v = e4[(size_t)l * (NB * 15) + base];
            ax += v.x; ay += v.y; az += v.z; aw += v.w;
        }
    }

    // ---------- phase 1b: stage weights as f16 quads (overlaps 1a latency) ----------
    for (int d = t; d < 68 * 30; d += 256) {
        const int k = d / 30, jj = d - k * 30;
        h4 w;
        if (k < 34) {
            w[0] = (_Float16)Wih[(0*30+jj)*34+k]; w[1] = (_Float16)Wih[(1*30+jj)*34+k];
            w[2] = (_Float16)Wih[(2*30+jj)*34+k]; w[3] = (_Float16)Wih[(3*30+jj)*34+k];
        } else if (k >= 36 && k < 66) {
            const int kk = k - 36;
            w[0] = (_Float16)Whh[(0*30+jj)*30+kk]; w[1] = (_Float16)Whh[(1*30+jj)*30+kk];
            w[2] = (_Float16)Whh[(2*30+jj)*30+kk]; w[3] = (_Float16)Whh[(3*30+jj)*30+kk];
        } else { w[0] = w[1] = w[2] = w[3] = (_Float16)0.f; }
        s_W4h[d] = w;
    }
    for (int d = t; d < 16 * 30; d += 256) {
        const int kc = d / 30, jj = d - kc * 30;
        h4 w;
        #pragma unroll
        for (int e = 0; e < 4; ++e) {
            float val = 0.f;
            if (kc < 8) { const int k = kc*4 + e; if (k < 30) val = Wg[jj*60 + k]; }
            else        { const int ks = (kc-8)*4 + e; if (ks < 30) val = Wg[jj*60 + 30 + ks]; }
            w[e] = (_Float16)val;
        }
        s_Wgh[d] = w;
    }
    for (int d = t; d < 8 * 30; d += 256) {
        const int kc = d / 30, jj = d - kc * 30;
        h4 w;
        #pragma unroll
        for (int e = 0; e < 4; ++e) {
            const int k = kc*4 + e;
            w[e] = (_Float16)((k <= 30) ? Wf1[jj*31 + k] : 0.f);
        }
        s_Wf1h[d] = w;
    }
    for (int d = t; d < 8 * 15; d += 256) {
        const int kc = d / 15, j2 = d - kc * 15;
        h4 w;
        #pragma unroll
        for (int e = 0; e < 4; ++e) {
            const int k = kc*4 + e;
            w[e] = (_Float16)((k < 30) ? Wf2[j2*30 + k] : 0.f);
        }
        s_Wf2h[d] = w;
    }
    for (int d = t; d < 15 * 30; d += 256) {
        const int ec = d / 30, jj = d - ec * 30;
        h4 w;
        #pragma unroll
        for (int e = 0; e < 4; ++e) w[e] = (_Float16)Wv[jj*60 + ec*4 + e];
        s_WvTh[d] = w;
    }
    if (t < 30) {
        float4 b;
        b.x = bih[0*30+t] + bhh[0*30+t]; b.y = bih[1*30+t] + bhh[1*30+t];
        b.z = bih[2*30+t] + bhh[2*30+t]; b.w = bih[3*30+t] + bhh[3*30+t];
        s_b4[t] = b; s_bg[t] = bg[t]; s_bf1[t] = bf1[t];
    }
    if (t < 15) { s_bf2[t] = bf2[t]; s_Wf3[t] = Wf3[t]; }
    if (t == 0) s_bf3v = bf3[0];
    // h0 init incl. pad cols 30 (se slot) / 31 (zero) -> finite (never NaN*0)
    for (int d = t; d < 512; d += 256) {
        const int row = d >> 5, cc = d & 31;
        s_h[row >> 2][0][(row & 3) * 32 + cc] =
            (cc < 30) ? hidden[(size_t)(b0 + row) * 30 + cc] : 0.f;
    }

    // write es (phase-1a results) to owner wave's LDS
    if (t < 240) {
        const float s = 1.f / 48.f;
        float4 r; r.x = ax*s; r.y = ay*s; r.z = az*s; r.w = aw*s;
        *(float4*)&s_wu[p1row >> 2].es[(p1row & 3) * 60 + p1c4 * 4] = r;
    }
    __syncthreads();   // weights + all es + h0 visible

    // ---------- V = es @ Wv.T + bv (softmax over singleton axis == 1 -> context = V) ----------
    float v0 = 0, v1 = 0;
    if (j < 30) {
        v0 = v1 = bv[j];                 // global (L2) read, once
        #pragma unroll
        for (int ec = 0; ec < 15; ++ec) {
            const h4 w = s_WvTh[ec*30 + j];
            const float4 d0 = LD4(&W.es[ra*60 + ec*4]);
            const float4 d1 = LD4(&W.es[rb*60 + ec*4]);
            v0 += (float)w[0]*d0.x + (float)w[1]*d0.y + (float)w[2]*d0.z + (float)w[3]*d0.w;
            v1 += (float)w[0]*d1.x + (float)w[1]*d1.y + (float)w[2]*d1.z + (float)w[3]*d1.w;
        }
    }
    // union overwrite: all reads above precede writes below (same wave, program order)
    if (j < 30) { W.d.V[ra*32 + j] = v0; W.d.V[rb*32 + j] = v1; }
    if (lane < 16) {      // rin0 = nan_to_num(y[:,0,:])
        const int r = lane >> 2, d = lane & 3;
        const float vv = y[(size_t)(bwg + r) * 52 + d];
        W.d.x[r*36 + d] = (vv == vv) ? vv : 0.f;
    }
    if (lane < 4) {       // permanent zero pads (avoid NaN*0 from garbage)
        W.d.x[lane*36 + 34] = 0.f; W.d.x[lane*36 + 35] = 0.f;
        W.d.V[lane*32 + 30] = 0.f; W.d.V[lane*32 + 31] = 0.f;
    }
    WBAR();

    // ---------- 12-step recurrence: wave-private, zero block barriers ----------
    float c0 = 0, c1 = 0;
    int cur = 0;
    #pragma unroll 1
    for (int i = 1; i <= 12; ++i) {
        const float se = (float)i * (1.f / 12.f);
        float* __restrict__ hc = &s_h[wid][cur][0];
        float* __restrict__ hn = &s_h[wid][cur ^ 1][0];

        // ---- A: gate = sig([h|V]@Wg.T+bg); enh -> x[:,4+j]
        if (j < 30) {
            float a0 = s_bg[j], a1 = a0;
            #pragma unroll
            for (int kc = 0; kc < 8; ++kc) {
                const h4 w = s_Wgh[kc*30 + j];
                const float4 d0 = LD4(&hc[ra*32 + kc*4]);
                const float4 d1 = LD4(&hc[rb*32 + kc*4]);
                a0 += (float)w[0]*d0.x + (float)w[1]*d0.y + (float)w[2]*d0.z + (float)w[3]*d0.w;
                a1 += (float)w[0]*d1.x + (float)w[1]*d1.y + (float)w[2]*d1.z + (float)w[3]*d1.w;
            }
            #pragma unroll
            for (int kc = 0; kc < 8; ++kc) {
                const h4 w = s_Wgh[(8+kc)*30 + j];
                const float4 d0 = LD4(&W.d.V[ra*32 + kc*4]);
                const float4 d1 = LD4(&W.d.V[rb*32 + kc*4]);
                a0 += (float)w[0]*d0.x + (float)w[1]*d0.y + (float)w[2]*d0.z + (float)w[3]*d0.w;
                a1 += (float)w[0]*d1.x + (float)w[1]*d1.y + (float)w[2]*d1.z + (float)w[3]*d1.w;
            }
            const float g0 = fast_sig(a0), g1 = fast_sig(a1);
            W.d.x[ra*36 + 4 + j] = g0*hc[ra*32+j] + (1.f-g0)*W.d.V[ra*32+j];
            W.d.x[rb*36 + 4 + j] = g1*hc[rb*32+j] + (1.f-g1)*W.d.V[rb*32+j];
        }
        WBAR();

        // ---- B: LSTM. 8 accum chains; f16 weight quads via fma_mix
        if (j < 30) {
            const float4 bb = s_b4[j];
            float i0=bb.x, f0=bb.y, g0=bb.z, o0=bb.w;
            float i1=bb.x, f1=bb.y, g1=bb.z, o1=bb.w;
#define LSTM_CHUNK(WK, D0, D1)                                                     \
            {                                                                       \
                const h4 wA = s_W4h[(WK+0)*30+j], wB = s_W4h[(WK+1)*30+j],          \
                         wC = s_W4h[(WK+2)*30+j], wD = s_W4h[(WK+3)*30+j];          \
                const float4 d0 = D0, d1 = D1;                                      \
                i0 += (float)wA[0]*d0.x + (float)wB[0]*d0.y + (float)wC[0]*d0.z + (float)wD[0]*d0.w; \
                f0 += (float)wA[1]*d0.x + (float)wB[1]*d0.y + (float)wC[1]*d0.z + (float)wD[1]*d0.w; \
                g0 += (float)wA[2]*d0.x + (float)wB[2]*d0.y + (float)wC[2]*d0.z + (float)wD[2]*d0.w; \
                o0 += (float)wA[3]*d0.x + (float)wB[3]*d0.y + (float)wC[3]*d0.z + (float)wD[3]*d0.w; \
                i1 += (float)wA[0]*d1.x + (float)wB[0]*d1.y + (float)wC[0]*d1.z + (float)wD[0]*d1.w; \
                f1 += (float)wA[1]*d1.x + (float)wB[1]*d1.y + (float)wC[1]*d1.z + (float)wD[1]*d1.w; \
                g1 += (float)wA[2]*d1.x + (float)wB[2]*d1.y + (float)wC[2]*d1.z + (float)wD[2]*d1.w; \
                o1 += (float)wA[3]*d1.x + (float)wB[3]*d1.y + (float)wC[3]*d1.z + (float)wD[3]*d1.w; \
            }
            #pragma unroll
            for (int kc = 0; kc < 9; ++kc) {     // x part: k 0..35 (pads zero-weighted)
                const int k = kc * 4;
                LSTM_CHUNK(k, LD4(&W.d.x[ra*36 + k]), LD4(&W.d.x[rb*36 + k]))
            }
            #pragma unroll
            for (int kc = 0; kc < 8; ++kc) {     // h part: k 0..31
                const int k = kc * 4;
                LSTM_CHUNK(36 + k, LD4(&hc[ra*32 + k]), LD4(&hc[rb*32 + k]))
            }
#undef LSTM_CHUNK
            const float cn0 = fast_sig(f0)*c0 + fast_sig(i0)*fast_tanh(g0); c0 = cn0;
            const float cn1 = fast_sig(f1)*c1 + fast_sig(i1)*fast_tanh(g1); c1 = cn1;
            hn[ra*32 + j] = fast_sig(o0)*fast_tanh(cn0);
            hn[rb*32 + j] = fast_sig(o1)*fast_tanh(cn1);
        } else {
            // pad lanes keep h cols 30/31 valid: [30]=se (fc1 folds se), [31]=0
            const float pv = (j == 30) ? se : 0.f;
            hn[ra*32 + j] = pv; hn[rb*32 + j] = pv;
        }
        WBAR();

        // prefetch next rin's y components (consumed in E)
        float py1 = 0, py2 = 0, py3 = 0;
        if (lane < 4) {
            const float* yp = y + (size_t)(bwg + lane) * 52 + i * 4;
            py1 = yp[1]; py2 = yp[2]; py3 = yp[3];
        }

        // ---- C: z1 = relu([h_new|se]@Wf1.T+bf1); z1 aliases dead old-h
        float* __restrict__ z1 = hc;
        if (j < 30) {
            float a0 = s_bf1[j], a1 = a0;
            #pragma unroll
            for (int kc = 0; kc < 8; ++kc) {     // last chunk reads [28,29,se,0]
                const h4 w = s_Wf1h[kc*30 + j];
                const float4 d0 = LD4(&hn[ra*32 + kc*4]);
                const float4 d1 = LD4(&hn[rb*32 + kc*4]);
                a0 += (float)w[0]*d0.x + (float)w[1]*d0.y + (float)w[2]*d0.z + (float)w[3]*d0.w;
                a1 += (float)w[0]*d1.x + (float)w[1]*d1.y + (float)w[2]*d1.z + (float)w[3]*d1.w;
            }
            z1[ra*32 + j] = fmaxf(a0, 0.f);
            z1[rb*32 + j] = fmaxf(a1, 0.f);
        }
        WBAR();

        // ---- D: z2 = relu(z1@Wf2.T+bf2) -> x[:,20..34] (dead enh space)
        if (j < 30) {
            const int j2 = (j < 15) ? j : j - 15;
            const int r  = ra + (j >= 15);
            float a = s_bf2[j2];
            #pragma unroll
            for (int kc = 0; kc < 8; ++kc) {     // z1 cols 30/31 hit zero weights
                const h4 w = s_Wf2h[kc*15 + j2];
                const float4 d = LD4(&z1[r*32 + kc*4]);
                a += (float)w[0]*d.x + (float)w[1]*d.y + (float)w[2]*d.z + (float)w[3]*d.w;
            }
            W.d.x[r*36 + 20 + j2] = fmaxf(a, 0.f);
        }
        WBAR();

        // ---- E: out = z2@Wf3.T+bf3; rin_next = [y[:,i,1:4], out]
        if (lane < 4) {
            float o = s_bf3v;
            #pragma unroll
            for (int k = 0; k < 15; ++k) o += s_Wf3[k] * W.d.x[lane*36 + 20 + k];
            out[(size_t)(i-1)*NB + bwg + lane] = o;
            W.d.x[lane*36 + 0] = py1; W.d.x[lane*36 + 1] = py2;
            W.d.x[lane*36 + 2] = py3; W.d.x[lane*36 + 3] = o;
        }
        WBAR();
        cur ^= 1;
    }
}

extern "C" void kernel_launch(void* const* d_in, const int* in_sizes, int n_in,
                              void* d_out, int out_size, void* d_ws, size_t ws_size,
                              hipStream_t stream) {
    (void)in_sizes; (void)n_in; (void)out_size; (void)d_ws; (void)ws_size;
    // 0 batch_ids, 1 y, 2 encoder_outputs, 3 hidden, 4 Wq, 5 bq, 6 Wk, 7 bk,
    // 8 Wv, 9 bv, 10 Wsa1, 11 bsa1, 12 Wsa2, 13 bsa2, 14 Wg, 15 bg,
    // 16 Wf1, 17 bf1, 18 Wf2, 19 bf2, 20 Wf3, 21 bf3, 22 W_ih, 23 b_ih,
    // 24 W_hh, 25 b_hh.  (Wq/bq/Wk/bk/Wsa* dead: softmax over size-1 axis == 1)
    decoder_kernel<<<dim3(NB / 16), dim3(256), 0, stream>>>(
        (const float*)d_in[1],  (const float*)d_in[2],  (const float*)d_in[3],
        (const float*)d_in[8],  (const float*)d_in[9],
        (const float*)d_in[14], (const float*)d_in[15],
        (const float*)d_in[16], (const float*)d_in[17],
        (const float*)d_in[18], (const float*)d_in[19],
        (const float*)d_in[20], (const float*)d_in[21],
        (const float*)d_in[22], (const float*)d_in[23],
        (const float*)d_in[24], (const float*)d_in[25],
        (float*)d_out);
}

// Round 6
// 88.330 us; speedup vs baseline: 1.7785x; 1.7785x over previous
//
#include <hip/hip_runtime.h>
#include <math.h>

#define NB 16384
typedef _Float16 f16;
typedef _Float16 f16x8 __attribute__((ext_vector_type(8)));
typedef _Float16 f16x4 __attribute__((ext_vector_type(4)));
typedef float f32x4 __attribute__((ext_vector_type(4)));

__device__ __forceinline__ float fast_sig(float v)  { return __builtin_amdgcn_rcpf(1.0f + __expf(-v)); }
__device__ __forceinline__ float fast_tanh(float v) { return 1.0f - 2.0f * __builtin_amdgcn_rcpf(1.0f + __expf(2.0f * v)); }

#define MFMA16(A, B, C) __builtin_amdgcn_mfma_f32_16x16x32_f16(A, B, C, 0, 0, 0)

// Per wave (= per block, 64 threads): 8 batch rows in a 16-row MFMA tile
// (rows 8-15 pad; they accumulate finite bias-garbage but MFMA rows are
// independent, so rows 0-7 stay exact). Weights live in VGPRs as f16
// B-fragments, loaded once. Activations round-trip through two tiny LDS
// buffers for the D-layout -> A-layout transpose.
// x16 row layout (72 halves, 144B stride): [0..3]=rin [4..33]=enh [34..63]=h [64..71]=scratch
__global__ __launch_bounds__(64, 2) void decoder_kernel(
    const float* __restrict__ y,      // [B,13,4]
    const float* __restrict__ enc,    // [48,B,60]
    const float* __restrict__ hidden, // [B,30]
    const float* __restrict__ Wv,  const float* __restrict__ bv,
    const float* __restrict__ Wg,  const float* __restrict__ bg,
    const float* __restrict__ Wf1, const float* __restrict__ bf1,
    const float* __restrict__ Wf2, const float* __restrict__ bf2,
    const float* __restrict__ Wf3, const float* __restrict__ bf3,
    const float* __restrict__ Wih, const float* __restrict__ bih,
    const float* __restrict__ Whh, const float* __restrict__ bhh,
    float* __restrict__ out)          // [12,B]
{
    __shared__ __align__(16) f16 x16[16][72];
    __shared__ __align__(16) f16 z1b[16][32];

    const int l = threadIdx.x;
    const int r = l & 15, g = l >> 4;        // A-row / D-col = r; k-block & D-row-group = g
    const int bw = blockIdx.x * 8;           // wave's first global batch row
    const f32x4 kz = {0.f, 0.f, 0.f, 0.f};

    // ---- zero LDS
    #pragma unroll
    for (int d = 0; d < 9; ++d)  ((unsigned*)x16)[d * 64 + l] = 0u;
    #pragma unroll
    for (int d = 0; d < 4; ++d)  ((unsigned*)z1b)[d * 64 + l] = 0u;

    // ---- phase 1: es = mean_L(enc) for 8 rows (fully coalesced float4)
    float a0x=0,a0y=0,a0z=0,a0w=0, a1x=0,a1y=0,a1z=0,a1w=0;
    {
        const float4* e4 = (const float4*)enc;
        const int u0r = l / 15, u0q = l - u0r * 15;
        const int u1 = 64 + l, u1r = u1 / 15, u1q = u1 - u1r * 15;
        const size_t o0 = (size_t)(bw + u0r) * 15 + u0q;
        const size_t o1 = (size_t)(bw + u1r) * 15 + u1q;
        #pragma unroll 4
        for (int L = 0; L < 48; ++L) {
            const size_t base = (size_t)L * (NB * 15);
            float4 v0 = e4[base + o0];
            a0x += v0.x; a0y += v0.y; a0z += v0.z; a0w += v0.w;
            if (l < 56) {
                float4 v1 = e4[base + o1];
                a1x += v1.x; a1y += v1.y; a1z += v1.z; a1w += v1.w;
            }
        }
    }

    // ---- load weight B-fragments (f16, persistent in VGPRs)
    // B-frag element e of lane l = W[k = kt*32 + g*8 + e][n = nt*16 + r]
    // (same (g,e)->k map used for A-frags => contraction is layout-invariant)
    f16x8 lf[2][8];                  // LSTM; t = gate*2 + jh; k: 0..33 Wih, 34..63 Whh
    #pragma unroll
    for (int kt = 0; kt < 2; ++kt)
        #pragma unroll
        for (int t = 0; t < 8; ++t) {
            const int gate = t >> 1, j = (t & 1) * 16 + r;
            const int trow = gate * 30 + j;
            f16x8 w;
            #pragma unroll
            for (int e = 0; e < 8; ++e) {
                const int k = kt * 32 + g * 8 + e;
                float val = 0.f;
                if (j < 30) val = (k < 34) ? Wih[trow * 34 + k] : Whh[trow * 30 + (k - 34)];
                w[e] = (f16)val;
            }
            lf[kt][t] = w;
        }
    f16x8 gf[2][2];                  // gate; kt0 over x16 cols 32..63 (kl>=2 -> h), kt1 over V
    #pragma unroll
    for (int nt = 0; nt < 2; ++nt) {
        const int j = nt * 16 + r;
        f16x8 w0, w1;
        #pragma unroll
        for (int e = 0; e < 8; ++e) {
            const int kl = g * 8 + e;
            w0[e] = (f16)((j < 30 && kl >= 2) ? Wg[j * 60 + (kl - 2)] : 0.f);
            w1[e] = (f16)((j < 30 && kl < 30) ? Wg[j * 60 + 30 + kl] : 0.f);
        }
        gf[0][nt] = w0; gf[1][nt] = w1;
    }
    f16x8 f1f[2];                    // fc1 over x16 cols 32..63 (kl>=2 -> h_new); se via bias
    #pragma unroll
    for (int nt = 0; nt < 2; ++nt) {
        const int j = nt * 16 + r;
        f16x8 w;
        #pragma unroll
        for (int e = 0; e < 8; ++e) {
            const int kl = g * 8 + e;
            w[e] = (f16)((j < 30 && kl >= 2) ? Wf1[j * 31 + (kl - 2)] : 0.f);
        }
        f1f[nt] = w;
    }
    f16x8 f2f;                       // fc2: z1(30) -> 15
    #pragma unroll
    for (int e = 0; e < 8; ++e) {
        const int kl = g * 8 + e;
        f2f[e] = (f16)((r < 15 && kl < 30) ? Wf2[r * 30 + kl] : 0.f);
    }
    f16x8 f3f;                       // fc3: z2(15) -> 1 (col 0 only)
    #pragma unroll
    for (int e = 0; e < 8; ++e) {
        const int kl = g * 8 + e;
        f3f[e] = (f16)((r == 0 && kl < 15) ? Wf3[kl] : 0.f);
    }
    f16x8 vf[2][2];                  // Wv: es(60) -> 30
    #pragma unroll
    for (int kt = 0; kt < 2; ++kt)
        #pragma unroll
        for (int nt = 0; nt < 2; ++nt) {
            const int j = nt * 16 + r;
            f16x8 w;
            #pragma unroll
            for (int e = 0; e < 8; ++e) {
                const int kl = kt * 32 + g * 8 + e;
                w[e] = (f16)((j < 30 && kl < 60) ? Wv[j * 60 + kl] : 0.f);
            }
            vf[kt][nt] = w;
        }

    // ---- biases (D-layout: depend on lane's col only)
    float bl[8], bgv[2], bf1v[2], wf1se[2];
    #pragma unroll
    for (int t = 0; t < 8; ++t) {
        const int gate = t >> 1, j = (t & 1) * 16 + r;
        bl[t] = (j < 30) ? bih[gate * 30 + j] + bhh[gate * 30 + j] : 0.f;
    }
    #pragma unroll
    for (int nt = 0; nt < 2; ++nt) {
        const int j = nt * 16 + r;
        bgv[nt]   = (j < 30) ? bg[j]  : 0.f;
        bf1v[nt]  = (j < 30) ? bf1[j] : 0.f;
        wf1se[nt] = (j < 30) ? Wf1[j * 31 + 30] : 0.f;
    }
    const float bf2v = (r < 15) ? bf2[r] : 0.f;
    const float bf3v = bf3[0];

    // ---- write es (scaled) into x16 rows 0..7 as f16
    {
        const float s = 1.f / 48.f;
        const int u0r = l / 15, u0q = l - u0r * 15;
        f16x4 h0 = {(f16)(a0x*s), (f16)(a0y*s), (f16)(a0z*s), (f16)(a0w*s)};
        *(f16x4*)&x16[u0r][u0q * 4] = h0;
        if (l < 56) {
            const int u1 = 64 + l, u1r = u1 / 15, u1q = u1 - u1r * 15;
            f16x4 h1 = {(f16)(a1x*s), (f16)(a1y*s), (f16)(a1z*s), (f16)(a1w*s)};
            *(f16x4*)&x16[u1r][u1q * 4] = h1;
        }
    }

    // ---- V = es @ Wv.T + bv  (softmax over singleton axis == 1 -> context = V)
    float VD[2][4];
    {
        const f16x8 ea0 = *(const f16x8*)((const char*)x16 + (size_t)r * 144 + g * 16);
        const f16x8 ea1 = *(const f16x8*)((const char*)x16 + (size_t)r * 144 + 64 + g * 16);
        f32x4 vd0 = MFMA16(ea0, vf[0][0], kz); vd0 = MFMA16(ea1, vf[1][0], vd0);
        f32x4 vd1 = MFMA16(ea0, vf[0][1], kz); vd1 = MFMA16(ea1, vf[1][1], vd1);
        const float bv0 = bv[r];                                     // nt0: j=r<16
        const float bv1 = (16 + r < 30) ? bv[16 + r] : 0.f;          // nt1
        #pragma unroll
        for (int q = 0; q < 4; ++q) { VD[0][q] = vd0[q] + bv0; VD[1][q] = vd1[q] + bv1; }
        // stage V through z1b to build the A-fragment (k = 0..31, pads zero)
        #pragma unroll
        for (int nt = 0; nt < 2; ++nt)
            #pragma unroll
            for (int q = 0; q < 4; ++q)
                z1b[4 * g + q][nt * 16 + r] = (f16)VD[nt][q];
    }
    const f16x8 va = *(const f16x8*)((const char*)z1b + (size_t)r * 64 + g * 16);

    // ---- h0 (D-layout regs + x16 h-region), rin0
    float hD[2][4];
    #pragma unroll
    for (int nt = 0; nt < 2; ++nt)
        #pragma unroll
        for (int q = 0; q < 4; ++q) {
            const int row = 4 * g + q, j = nt * 16 + r;
            hD[nt][q] = (row < 8 && j < 30) ? hidden[(size_t)(bw + row) * 30 + j] : 0.f;
            x16[row][34 + nt * 16 + r] = (f16)hD[nt][q];   // nt1 r>=14 -> scratch cols 64/65
        }
    if (l < 8) {
        const float* yp = y + (size_t)(bw + l) * 52;
        #pragma unroll
        for (int d = 0; d < 4; ++d) {
            float v = yp[d];
            x16[l][d] = (f16)((v == v) ? v : 0.f);
        }
    }

    // ---- 12-step recurrence (wave-private; no block barriers anywhere)
    float c[2][4] = {{0,0,0,0},{0,0,0,0}};
    #pragma unroll 1
    for (int i = 1; i <= 12; ++i) {
        const float se = (float)i * (1.f / 12.f);

        // A: gate = sig([h|V] @ Wg.T + bg); enh -> x16 cols 4..33
        // (xhg's cols 32,33 are stale enh[28,29] — zero-weighted in gf[0])
        {
            const f16x8 xhg = *(const f16x8*)((const char*)x16 + (size_t)r * 144 + 64 + g * 16);
            f32x4 gd0 = MFMA16(xhg, gf[0][0], kz); gd0 = MFMA16(va, gf[1][0], gd0);
            f32x4 gd1 = MFMA16(xhg, gf[0][1], kz); gd1 = MFMA16(va, gf[1][1], gd1);
            #pragma unroll
            for (int nt = 0; nt < 2; ++nt)
                #pragma unroll
                for (int q = 0; q < 4; ++q) {
                    const float a  = (nt ? gd1[q] : gd0[q]) + bgv[nt];
                    const float gt = fast_sig(a);
                    const float enh = gt * hD[nt][q] + (1.f - gt) * VD[nt][q];
                    const int j = nt * 16 + r;
                    if (j < 30) x16[4 * g + q][4 + j] = (f16)enh;
                }
        }

        // B: LSTM. BOTH A-tiles reloaded AFTER section A's enh stores —
        // cols 32,33 of tile 1 are enh[28,29] and must be fresh (r5 bug).
        {
            const f16x8 xa0 = *(const f16x8*)((const char*)x16 + (size_t)r * 144 + g * 16);
            const f16x8 xa1 = *(const f16x8*)((const char*)x16 + (size_t)r * 144 + 64 + g * 16);
            f32x4 ld[8];
            #pragma unroll
            for (int t = 0; t < 8; ++t) {
                ld[t] = MFMA16(xa0, lf[0][t], kz);
                ld[t] = MFMA16(xa1, lf[1][t], ld[t]);
            }
            #pragma unroll
            for (int jh = 0; jh < 2; ++jh)
                #pragma unroll
                for (int q = 0; q < 4; ++q) {
                    const float ii = fast_sig (ld[0 + jh][q] + bl[0 + jh]);
                    const float ff = fast_sig (ld[2 + jh][q] + bl[2 + jh]);
                    const float gg = fast_tanh(ld[4 + jh][q] + bl[4 + jh]);
                    const float oo = fast_sig (ld[6 + jh][q] + bl[6 + jh]);
                    const float cn = ff * c[jh][q] + ii * gg;
                    c[jh][q] = cn;
                    const float hn = oo * fast_tanh(cn);
                    hD[jh][q] = hn;
                    x16[4 * g + q][34 + jh * 16 + r] = (f16)hn;  // jh1 r>=14 -> scratch
                }
        }

        // C: z1 = relu([h_new|se] @ Wf1.T + bf1)   (se folded into dynamic bias)
        {
            const f16x8 hn = *(const f16x8*)((const char*)x16 + (size_t)r * 144 + 64 + g * 16);
            f32x4 d0 = MFMA16(hn, f1f[0], kz);
            f32x4 d1 = MFMA16(hn, f1f[1], kz);
            #pragma unroll
            for (int nt = 0; nt < 2; ++nt)
                #pragma unroll
                for (int q = 0; q < 4; ++q) {
                    const float z = fmaxf((nt ? d1[q] : d0[q]) + bf1v[nt] + se * wf1se[nt], 0.f);
                    z1b[4 * g + q][nt * 16 + r] = (f16)z;
                }
        }

        // D: z2 = relu(z1 @ Wf2.T + bf2) -> z1b cols 0..15
        {
            const f16x8 z1a = *(const f16x8*)((const char*)z1b + (size_t)r * 64 + g * 16);
            f32x4 d = MFMA16(z1a, f2f, kz);
            #pragma unroll
            for (int q = 0; q < 4; ++q)
                z1b[4 * g + q][r] = (f16)fmaxf(d[q] + bf2v, 0.f);
        }

        // E: out = z2 @ Wf3.T + bf3 (stale z1 cols 16..31 killed by zero weights)
        {
            const f16x8 z2a = *(const f16x8*)((const char*)z1b + (size_t)r * 64 + g * 16);
            f32x4 od = MFMA16(z2a, f3f, kz);
            if (r == 0 && g < 2) {
                #pragma unroll
                for (int q = 0; q < 4; ++q) {
                    const float o = od[q] + bf3v;
                    out[(size_t)(i - 1) * NB + bw + 4 * g + q] = o;
                    x16[4 * g + q][3] = (f16)o;           // rin[3] = out
                }
            }
            if (l < 8) {                                   // rin[0..2] = y[:, i, 1:4]
                const float* yp = y + (size_t)(bw + l) * 52 + (size_t)i * 4;
                x16[l][0] = (f16)yp[1];
                x16[l][1] = (f16)yp[2];
                x16[l][2] = (f16)yp[3];
            }
        }
    }
}

extern "C" void kernel_launch(void* const* d_in, const int* in_sizes, int n_in,
                              void* d_out, int out_size, void* d_ws, size_t ws_size,
                              hipStream_t stream) {
    (void)in_sizes; (void)n_in; (void)out_size; (void)d_ws; (void)ws_size;
    // 0 batch_ids, 1 y, 2 encoder_outputs, 3 hidden, 4 Wq, 5 bq, 6 Wk, 7 bk,
    // 8 Wv, 9 bv, 10 Wsa1, 11 bsa1, 12 Wsa2, 13 bsa2, 14 Wg, 15 bg,
    // 16 Wf1, 17 bf1, 18 Wf2, 19 bf2, 20 Wf3, 21 bf3, 22 W_ih, 23 b_ih,
    // 24 W_hh, 25 b_hh.  (Wq/bq/Wk/bk/Wsa* dead: softmax over size-1 axis == 1)
    decoder_kernel<<<dim3(NB / 8), dim3(64), 0, stream>>>(
        (const float*)d_in[1],  (const float*)d_in[2],  (const float*)d_in[3],
        (const float*)d_in[8],  (const float*)d_in[9],
        (const float*)d_in[14], (const float*)d_in[15],
        (const float*)d_in[16], (const float*)d_in[17],
        (const float*)d_in[18], (const float*)d_in[19],
        (const float*)d_in[20], (const float*)d_in[21],
        (const float*)d_in[22], (const float*)d_in[23],
        (const float*)d_in[24], (const float*)d_in[25],
        (float*)d_out);
}